// Round 1
// baseline (94.378 us; speedup 1.0000x reference)
//
#include <hip/hip_runtime.h>
#include <math.h>

#define FRAME_LEN 256
#define HOP       128
#define NBINS     129
#define T_OUT     128
#define M_OUT     64
#define SIGLEN    160000

// One block (64 threads = 1 wave) per (signal, t_out).
// Computes 2 frames' rffts via one packed complex FFT, log-mag, clip,
// bilinear-interp to 64 mel outputs.
__global__ __launch_bounds__(64) void spectro_kernel(const float* __restrict__ x,
                                                     float* __restrict__ out) {
    const int blk = blockIdx.x;          // sig*128 + t
    const int t   = blk & (T_OUT - 1);
    const int sig = blk >> 7;            // 0..511  (b*16+s)
    const int tid = threadIdx.x;         // 0..63

    __shared__ float  xs[384];
    __shared__ float2 buf[256];
    __shared__ float2 tw[128];
    __shared__ float  L0[NBINS];
    __shared__ float  L1[NBINS];

    // ---- bilinear source coords along t (jax.image.resize half-pixel) ----
    const float scale_t = 1250.0f / 128.0f;              // 9.765625 exact
    const float src_t = ((float)t + 0.5f) * scale_t - 0.5f;
    const int   t0 = (int)floorf(src_t);                 // in [4, 1244]
    const float ft = src_t - (float)t0;

    const long base = (long)sig * SIGLEN + (long)t0 * HOP;

    // ---- stage 384 samples (frame t0 and t0+1 overlap by 128) ----
    for (int i = tid; i < 192; i += 64) {
        float2 v = *(const float2*)(x + base + 2 * i);   // 8B-aligned, coalesced
        xs[2 * i]     = v.x;
        xs[2 * i + 1] = v.y;
    }
    // ---- twiddles tw[j] = exp(-2*pi*i*j/256) ----
    for (int j = tid; j < 128; j += 64) {
        float ang = -2.0f * (float)M_PI * (float)j * (1.0f / 256.0f);
        tw[j] = make_float2(cosf(ang), sinf(ang));
    }
    __syncthreads();

    // ---- window + pack two real frames into one complex seq, bit-rev ----
    for (int n = tid; n < 256; n += 64) {
        float w = 0.5f - 0.5f * cosf((float)n * (2.0f * (float)M_PI / 256.0f));
        float2 z = make_float2(w * xs[n], w * xs[n + HOP]);
        int r = (int)(__brev((unsigned)n) >> 24);
        buf[r] = z;
    }
    __syncthreads();

    // ---- 8-stage radix-2 DIT FFT ----
    for (int s = 1; s <= 8; ++s) {
        const int half = 1 << (s - 1);
        const int tws  = 8 - s;                 // twiddle index stride shift
        for (int b = tid; b < 128; b += 64) {
            const int grp = b >> (s - 1);
            const int j   = b & (half - 1);
            const int pos = (grp << s) + j;
            float2 u = buf[pos];
            float2 v = buf[pos + half];
            float2 w = tw[j << tws];
            float vr = v.x * w.x - v.y * w.y;
            float vi = v.x * w.y + v.y * w.x;
            buf[pos]        = make_float2(u.x + vr, u.y + vi);
            buf[pos + half] = make_float2(u.x - vr, u.y - vi);
        }
        __syncthreads();
    }

    // ---- unpack rfft of both frames, log-mag, clip ----
    for (int k = tid; k <= 128; k += 64) {
        float2 A = buf[k];
        float2 B = buf[(256 - k) & 255];
        float f0r = 0.5f * (A.x + B.x), f0i = 0.5f * (A.y - B.y);
        float f1r = 0.5f * (A.y + B.y), f1i = 0.5f * (B.x - A.x);
        float l0 = logf(sqrtf(f0r * f0r + f0i * f0i) + 1e-9f);
        float l1 = logf(sqrtf(f1r * f1r + f1i * f1i) + 1e-9f);
        L0[k] = fminf(fmaxf(l0, -12.0f), 12.0f);
        L1[k] = fminf(fmaxf(l1, -12.0f), 12.0f);
    }
    __syncthreads();

    // ---- bilinear over mel axis, blend the two frames, clip, store ----
    const int m = tid;                                   // 0..63
    const float scale_m = 129.0f / 64.0f;                // 2.015625 exact
    const float src_m = ((float)m + 0.5f) * scale_m - 0.5f;
    const int   m0 = (int)floorf(src_m);                 // in [0, 127]
    const float fm = src_m - (float)m0;

    float a = L0[m0] * (1.0f - fm) + L0[m0 + 1] * fm;
    float b = L1[m0] * (1.0f - fm) + L1[m0 + 1] * fm;
    float val = a * (1.0f - ft) + b * ft;
    val = fminf(fmaxf(val, -12.0f), 12.0f);
    out[(long)blk * M_OUT + m] = val;
}

extern "C" void kernel_launch(void* const* d_in, const int* in_sizes, int n_in,
                              void* d_out, int out_size, void* d_ws, size_t ws_size,
                              hipStream_t stream) {
    const float* x = (const float*)d_in[0];
    float* out = (float*)d_out;
    const int nblocks = 512 * T_OUT;   // (32*16) signals * 128 output rows
    spectro_kernel<<<dim3(nblocks), dim3(64), 0, stream>>>(x, out);
}

// Round 2
// 55.597 us; speedup vs baseline: 1.6975x; 1.6975x over previous
//
#include <hip/hip_runtime.h>
#include <math.h>

#define HOP     128
#define SIGLEN  160000
#define T_OUT   128
#define M_OUT   64
// LDS pad: +1 float per 32 to break power-of-2 stride bank conflicts
#define P(p) ((p) + ((p) >> 5))

// d_ws layout: win[256] float, then twf[256] float2 (exp(-2*pi*i*n/256))
__global__ __launch_bounds__(256) void init_tables(float* __restrict__ ws) {
    const int n = threadIdx.x;                     // 0..255
    float a = (float)n * (2.0f * (float)M_PI / 256.0f);
    float s, c;
    sincosf(a, &s, &c);
    ws[n] = 0.5f - 0.5f * c;                       // periodic Hann
    float2* twf = (float2*)(ws + 256);
    twf[n] = make_float2(c, -s);
}

// One block (1 wave, 64 threads) per (signal, t_out) row.
// Packed complex FFT-256 computes both needed frames' rffts at once.
__global__ __launch_bounds__(64) void spectro_kernel(const float* __restrict__ x,
                                                     const float* __restrict__ ws,
                                                     float* __restrict__ out) {
    const int blk = blockIdx.x;          // sig*128 + t
    const int t   = blk & (T_OUT - 1);
    const int sig = blk >> 7;
    const int tid = threadIdx.x;         // 0..63

    __shared__ float re[264], im[264];   // P(255)=262
    __shared__ float twr[132], twi[132]; // P(127)=130
    __shared__ float L0[132], L1[132];

    // bilinear source coords along t (half-pixel centers)
    const float src_t = ((float)t + 0.5f) * (1250.0f / 128.0f) - 0.5f;
    const int   t0 = (int)floorf(src_t);            // in [4, 1244]
    const float ft = src_t - (float)t0;
    const long  base = (long)sig * SIGLEN + (long)t0 * HOP;

    // stage twiddles 0..127 into LDS (SoA + pad)
    const float2* twf = (const float2*)(ws + 256);
    #pragma unroll
    for (int k = 0; k < 2; ++k) {
        int idx = tid + 64 * k;
        float2 w = twf[idx];
        twr[P(idx)] = w.x;
        twi[P(idx)] = w.y;
    }

    // load + window + pack two real frames (offset 0 and 128) as z = f0 + i*f1,
    // write bit-reversed. n = 4*tid + k; overlap re-read hits L1.
    float4 xa = *(const float4*)(x + base + 4 * tid);
    float4 xb = *(const float4*)(x + base + 128 + 4 * tid);
    float4 wv = *(const float4*)(ws + 4 * tid);
    const int rt = (int)(__brev((unsigned)tid) >> 26);   // brev6(tid)
    float xaf[4] = {xa.x, xa.y, xa.z, xa.w};
    float xbf[4] = {xb.x, xb.y, xb.z, xb.w};
    float wvf[4] = {wv.x, wv.y, wv.z, wv.w};
    #pragma unroll
    for (int k = 0; k < 4; ++k) {
        int r = rt | ((k & 1) << 7) | ((k & 2) << 5);    // brev8(4*tid+k)
        re[P(r)] = wvf[k] * xaf[k];
        im[P(r)] = wvf[k] * xbf[k];
    }
    __syncthreads();

    // 4 fused double-stages (radix-2 stages s and s+1 in registers).
    // Stage-(s+1) upper twiddle = lower twiddle * (-i), derived in-reg.
    #pragma unroll
    for (int s = 1; s <= 7; s += 2) {
        const int half = 1 << (s - 1);
        const int j = tid & (half - 1);
        const int g = tid >> (s - 1);
        const int b0 = (g << (s + 1)) + j;
        const int p0 = b0, p1 = b0 + half, p2 = b0 + 2 * half, p3 = b0 + 3 * half;
        float x0r = re[P(p0)], x0i = im[P(p0)];
        float x1r = re[P(p1)], x1i = im[P(p1)];
        float x2r = re[P(p2)], x2i = im[P(p2)];
        float x3r = re[P(p3)], x3i = im[P(p3)];
        const int ia = j << (8 - s);
        const int ib = j << (7 - s);
        float ca = twr[P(ia)], sa = twi[P(ia)];
        float cb = twr[P(ib)], sb = twi[P(ib)];
        // stage s: pairs (p0,p1) and (p2,p3), twiddle w_a
        float t1r = ca * x1r - sa * x1i, t1i = ca * x1i + sa * x1r;
        float t3r = ca * x3r - sa * x3i, t3i = ca * x3i + sa * x3r;
        float A0r = x0r + t1r, A0i = x0i + t1i;
        float A1r = x0r - t1r, A1i = x0i - t1i;
        float A2r = x2r + t3r, A2i = x2i + t3i;
        float A3r = x2r - t3r, A3i = x2i - t3i;
        // stage s+1: pairs (p0,p2) tw w_b, (p1,p3) tw w_c = w_b*(-i)
        float ur = cb * A2r - sb * A2i, ui = cb * A2i + sb * A2r;
        float vr = sb * A3r + cb * A3i, vi = sb * A3i - cb * A3r;
        re[P(p0)] = A0r + ur;  im[P(p0)] = A0i + ui;
        re[P(p2)] = A0r - ur;  im[P(p2)] = A0i - ui;
        re[P(p1)] = A1r + vr;  im[P(p1)] = A1i + vi;
        re[P(p3)] = A1r - vr;  im[P(p3)] = A1i - vi;
        __syncthreads();
    }

    // unpack both rffts via conjugate symmetry; 0.5*log(p) == log(sqrt(p));
    // +1e-9 only matters below the -12 clip floor (diff < 2e-4 above it)
    #pragma unroll
    for (int kk = 0; kk < 2; ++kk) {
        int k = tid + 64 * kk;                 // 0..127
        int k2 = (256 - k) & 255;
        float Ar = re[P(k)],  Ai = im[P(k)];
        float Br = re[P(k2)], Bi = im[P(k2)];
        float f0r = 0.5f * (Ar + Br), f0i = 0.5f * (Ai - Bi);
        float f1r = 0.5f * (Ai + Bi), f1i = 0.5f * (Br - Ar);
        float l0 = 0.5f * __logf(f0r * f0r + f0i * f0i);
        float l1 = 0.5f * __logf(f1r * f1r + f1i * f1i);
        L0[k] = fminf(fmaxf(l0, -12.0f), 12.0f);
        L1[k] = fminf(fmaxf(l1, -12.0f), 12.0f);
    }
    if (tid == 0) {                            // Nyquist bin (k=128, purely real)
        float Ar = re[P(128)], Ai = im[P(128)];
        float l0 = 0.5f * __logf(Ar * Ar);
        float l1 = 0.5f * __logf(Ai * Ai);
        L0[128] = fminf(fmaxf(l0, -12.0f), 12.0f);
        L1[128] = fminf(fmaxf(l1, -12.0f), 12.0f);
    }
    __syncthreads();

    // bilinear over mel axis + blend the two frames, clip, store
    const int m = tid;
    const float src_m = ((float)m + 0.5f) * (129.0f / 64.0f) - 0.5f;
    const int   m0 = (int)floorf(src_m);
    const float fm = src_m - (float)m0;
    float a = L0[m0] * (1.0f - fm) + L0[m0 + 1] * fm;
    float b = L1[m0] * (1.0f - fm) + L1[m0 + 1] * fm;
    float val = a * (1.0f - ft) + b * ft;
    val = fminf(fmaxf(val, -12.0f), 12.0f);
    out[(long)blk * M_OUT + m] = val;
}

extern "C" void kernel_launch(void* const* d_in, const int* in_sizes, int n_in,
                              void* d_out, int out_size, void* d_ws, size_t ws_size,
                              hipStream_t stream) {
    const float* x = (const float*)d_in[0];
    float* ws = (float*)d_ws;
    float* out = (float*)d_out;
    init_tables<<<dim3(1), dim3(256), 0, stream>>>(ws);
    const int nblocks = 512 * T_OUT;   // (32*16) signals * 128 rows
    spectro_kernel<<<dim3(nblocks), dim3(64), 0, stream>>>(x, ws, out);
}

// Round 5
// 51.766 us; speedup vs baseline: 1.8232x; 1.0740x over previous
//
#include <hip/hip_runtime.h>
#include <math.h>

#define HOP     128
#define SIGLEN  160000
#define T_OUT   128

// d_ws: ws[0..255] = periodic Hann window; then float2 twf[256] = exp(-2*pi*i*k/256)
__global__ __launch_bounds__(256) void init_tables(float* __restrict__ ws) {
    const int n = threadIdx.x;
    float a = (float)n * (2.0f * (float)M_PI / 256.0f);
    float s, c;
    sincosf(a, &s, &c);
    ws[n] = 0.5f - 0.5f * c;
    float2* twf = (float2*)(ws + 256);
    twf[n] = make_float2(c, -s);
}

__device__ __forceinline__ float2 cmul(float2 a, float2 b) {
    return make_float2(a.x * b.x - a.y * b.y, a.x * b.y + a.y * b.x);
}

// radix-4 DIF butterfly: y_q = sum_j in_j * (-i)^(j*q)
__device__ __forceinline__ void r4(float2 a, float2 b, float2 c, float2 d,
                                   float2& y0, float2& y1, float2& y2, float2& y3) {
    float t0r = a.x + c.x, t0i = a.y + c.y;
    float t1r = a.x - c.x, t1i = a.y - c.y;
    float t2r = b.x + d.x, t2i = b.y + d.y;
    float t3r = b.x - d.x, t3i = b.y - d.y;
    y0 = make_float2(t0r + t2r, t0i + t2i);
    y2 = make_float2(t0r - t2r, t0i - t2i);
    y1 = make_float2(t1r + t3i, t1i - t3r);   // t1 - i*t3
    y3 = make_float2(t1r - t3i, t1i + t3r);   // t1 + i*t3
}

#define PAD4(a) ((a) + ((a) >> 4))

// One block = one wave (64 threads) per (signal, t_out) row.
// Packed complex FFT-256 (re=frame t0, im=frame t0+1), radix-4, 4 pts/thread,
// 3 conflict-free float2 LDS transposes.
__global__ __launch_bounds__(64) void spectro_kernel(const float* __restrict__ x,
                                                     const float* __restrict__ ws,
                                                     float* __restrict__ out) {
    const int blk = blockIdx.x;
    const int t   = blk & (T_OUT - 1);
    const int sig = blk >> 7;
    const int tid = threadIdx.x;

    __shared__ float2 buf[272];   // transpose / X buffer (padded indices <= 270)
    __shared__ float2 L[132];     // (L0,L1) per bin, 129 bins

    const float src_t = ((float)t + 0.5f) * (1250.0f / 128.0f) - 0.5f;
    const int   t0 = (int)src_t;              // src_t >= 4.38 -> trunc == floor
    const float ft = src_t - (float)t0;
    const float* xb = x + (long)sig * SIGLEN + (long)t0 * HOP;
    const float2* twf = (const float2*)(ws + 256);

    // ---- load 6 coalesced dwords (384 unique samples) + window ----
    float v0 = xb[tid], v1 = xb[tid + 64], v2 = xb[tid + 128];
    float v3 = xb[tid + 192], v4 = xb[tid + 256], v5 = xb[tid + 320];
    float w0 = ws[tid], w1 = ws[tid + 64], w2 = ws[tid + 128], w3 = ws[tid + 192];

    // packed z[n] = w[n]*f0[n] + i*w[n]*f1[n], n = tid + 64c
    float2 a = make_float2(w0 * v0, w0 * v2);
    float2 b = make_float2(w1 * v1, w1 * v3);
    float2 c = make_float2(w2 * v2, w2 * v4);
    float2 d = make_float2(w3 * v3, w3 * v5);

    // ---- stage 1 (distance 64), twiddle W256^(tid*q) ----
    float2 y0, y1, y2, y3;
    r4(a, b, c, d, y0, y1, y2, y3);
    y1 = cmul(y1, twf[tid]);
    y2 = cmul(y2, twf[2 * tid]);
    y3 = cmul(y3, twf[3 * tid]);

    // transpose 1: q-major layout, addr = 64q + n  (uniform banks, no pad)
    buf[tid]       = y0;
    buf[64 + tid]  = y1;
    buf[128 + tid] = y2;
    buf[192 + tid] = y3;
    __syncthreads();

    // ---- stage 2: thread (q0 = tid>>4, s = tid&15), distance 16 ----
    {
        const int q0 = tid >> 4, s = tid & 15;
        const int base = 64 * q0 + s;
        float2 A = buf[base], B = buf[base + 16], C = buf[base + 32], D = buf[base + 48];
        r4(A, B, C, D, y0, y1, y2, y3);
        y1 = cmul(y1, twf[4 * s]);            // W64^(s*r)
        y2 = cmul(y2, twf[8 * s]);
        y3 = cmul(y3, twf[12 * s]);
        // transpose 2: addr = 64q0 + 16r + s, padded
        buf[PAD4(64 * q0 + s)]      = y0;
        buf[PAD4(64 * q0 + 16 + s)] = y1;
        buf[PAD4(64 * q0 + 32 + s)] = y2;
        buf[PAD4(64 * q0 + 48 + s)] = y3;
    }
    __syncthreads();

    // ---- stage 3: thread (f = tid>>2, u = tid&3), distance 4 ----
    {
        const int f = tid >> 2, u = tid & 3;
        const int base = 16 * f + u;
        float2 A = buf[PAD4(base)], B = buf[PAD4(base + 4)];
        float2 C = buf[PAD4(base + 8)], D = buf[PAD4(base + 12)];
        r4(A, B, C, D, y0, y1, y2, y3);
        y1 = cmul(y1, twf[16 * u]);           // W16^(u*p)
        y2 = cmul(y2, twf[32 * u]);
        y3 = cmul(y3, twf[48 * u]);
        // transpose 3: addr = 16f + 4p + u, padded
        buf[PAD4(16 * f + u)]      = y0;
        buf[PAD4(16 * f + 4 + u)]  = y1;
        buf[PAD4(16 * f + 8 + u)]  = y2;
        buf[PAD4(16 * f + 12 + u)] = y3;
    }
    __syncthreads();

    // ---- stage 4 (distance 1, no twiddle) + natural-order X write ----
    {
        const int g4 = 4 * tid;
        float2 A = buf[PAD4(g4)], B = buf[PAD4(g4 + 1)];
        float2 C = buf[PAD4(g4 + 2)], D = buf[PAD4(g4 + 3)];
        r4(A, B, C, D, y0, y1, y2, y3);
        // digits: q = tid>>4, r = (tid>>2)&3, p = tid&3; m = 64k + 16p + 4r + q
        const int mbase = 16 * (tid & 3) + 4 * ((tid >> 2) & 3) + (tid >> 4);
        __syncthreads();                      // X write reuses buf
        buf[mbase]       = y0;
        buf[mbase + 64]  = y1;
        buf[mbase + 128] = y2;
        buf[mbase + 192] = y3;
    }
    __syncthreads();

    // ---- unpack packed rfft pair, log-mag, clip: bins tid and tid+64 ----
    #pragma unroll
    for (int kk = 0; kk < 2; ++kk) {
        const int k = tid + 64 * kk;
        float2 A = buf[k];
        float2 B = buf[(256 - k) & 255];
        float f0r = 0.5f * (A.x + B.x), f0i = 0.5f * (A.y - B.y);
        float f1r = 0.5f * (A.y + B.y), f1i = 0.5f * (B.x - A.x);
        float l0 = 0.5f * __logf(f0r * f0r + f0i * f0i);
        float l1 = 0.5f * __logf(f1r * f1r + f1i * f1i);
        l0 = fminf(fmaxf(l0, -12.0f), 12.0f);
        l1 = fminf(fmaxf(l1, -12.0f), 12.0f);
        L[k] = make_float2(l0, l1);
    }
    if (tid == 0) {                           // Nyquist bin (purely real)
        float2 A = buf[128];
        float l0 = 0.5f * __logf(A.x * A.x);
        float l1 = 0.5f * __logf(A.y * A.y);
        L[128] = make_float2(fminf(fmaxf(l0, -12.0f), 12.0f),
                             fminf(fmaxf(l1, -12.0f), 12.0f));
    }
    __syncthreads();

    // ---- bilinear over mel axis + t-blend, clip, coalesced store ----
    const float src_m = ((float)tid + 0.5f) * (129.0f / 64.0f) - 0.5f;
    const int   m0 = (int)src_m;              // src_m >= 0.5 -> trunc == floor
    const float fm = src_m - (float)m0;
    float2 Ld = L[m0], Lu = L[m0 + 1];
    float va = Ld.x * (1.0f - fm) + Lu.x * fm;
    float vb = Ld.y * (1.0f - fm) + Lu.y * fm;
    float val = va * (1.0f - ft) + vb * ft;
    val = fminf(fmaxf(val, -12.0f), 12.0f);
    out[(long)blk * 64 + tid] = val;
}

extern "C" void kernel_launch(void* const* d_in, const int* in_sizes, int n_in,
                              void* d_out, int out_size, void* d_ws, size_t ws_size,
                              hipStream_t stream) {
    const float* x = (const float*)d_in[0];
    float* ws = (float*)d_ws;
    float* out = (float*)d_out;
    init_tables<<<dim3(1), dim3(256), 0, stream>>>(ws);
    spectro_kernel<<<dim3(512 * T_OUT), dim3(64), 0, stream>>>(x, ws, out);
}